// Round 15
// baseline (264.180 us; speedup 1.0000x reference)
//
#include <hip/hip_runtime.h>

typedef unsigned short u16;
typedef __bf16 bf16x8 __attribute__((ext_vector_type(8)));
typedef float f32x4 __attribute__((ext_vector_type(4)));
typedef float f32x16 __attribute__((ext_vector_type(16)));

static __device__ __forceinline__ u16 f2bf(float f) {
  unsigned u = __builtin_bit_cast(unsigned, f);
  u += 0x7fffu + ((u >> 16) & 1u);
  return (u16)(u >> 16);
}
static __device__ __forceinline__ float bf2f(u16 u) {
  return __builtin_bit_cast(float, (unsigned)u << 16);
}
static __device__ __forceinline__ unsigned cvtpk(float lo, float hi) {
  unsigned r;
  asm("v_cvt_pk_bf16_f32 %0, %1, %2" : "=v"(r) : "v"(lo), "v"(hi));
  return r;
}
static __device__ __forceinline__ float fexp2(float x) {
  float r;
  asm("v_exp_f32 %0, %1" : "=v"(r) : "v"(x));
  return r;
}

static __device__ __forceinline__ void gload_lds16(const void* g, void* l) {
  __builtin_amdgcn_global_load_lds((const __attribute__((address_space(1))) unsigned int*)g,
                                   (__attribute__((address_space(3))) unsigned int*)l,
                                   16, 0, 0);
}

// ---------------------------------------------------------------------------
// fp32 -> bf16 conversion for X, Wq, Wk, Wv, Wo (one launch)
// ---------------------------------------------------------------------------
__global__ __launch_bounds__(256) void cvt_all(
    const float* __restrict__ X, const float* __restrict__ Wq, const float* __restrict__ Wk,
    const float* __restrict__ Wv, const float* __restrict__ Wo,
    u16* __restrict__ oX, u16* __restrict__ oWq, u16* __restrict__ oWk,
    u16* __restrict__ oWv, u16* __restrict__ oWo) {
  const int b = blockIdx.x;
  const float* s; u16* d; int lb;
  if (b < 1024)      { s = X;  d = oX;  lb = b; }
  else if (b < 2048) { s = Wq; d = oWq; lb = b - 1024; }
  else if (b < 2304) { s = Wk; d = oWk; lb = b - 2048; }
  else if (b < 2560) { s = Wv; d = oWv; lb = b - 2304; }
  else               { s = Wo; d = oWo; lb = b - 2560; }
  const int base = lb * 4096 + threadIdx.x * 4;
#pragma unroll
  for (int j = 0; j < 4; ++j) {
    const int off = base + j * 1024;
    float4 v = *(const float4*)(s + off);
    ushort4 u;
    u.x = f2bf(v.x); u.y = f2bf(v.y); u.z = f2bf(v.z); u.w = f2bf(v.w);
    *(ushort4*)(d + off) = u;
  }
}

// ---------------------------------------------------------------------------
// Fused QKV GEMM over virtual N=3072: [Wq | Wk | Wv]. BM=64 x BN=128, BK=64.
// ---------------------------------------------------------------------------
__global__ __launch_bounds__(256, 4) void gemm_qkv(
    const u16* __restrict__ A, const u16* __restrict__ Bq, const u16* __restrict__ Bk,
    const u16* __restrict__ Bv, u16* __restrict__ Qb, u16* __restrict__ Kb,
    u16* __restrict__ Vt, const float* __restrict__ cosp, const float* __restrict__ sinp) {
  __shared__ u16 As[64 * 64];
  __shared__ u16 Bs[128 * 64];
  const int tid = threadIdx.x;
  const int lane = tid & 63, w = tid >> 6;
  const int wr = w >> 1, wc = w & 1;
  const int lr = lane & 15, lq = lane >> 4;
  const int bm = blockIdx.y << 6;
  const int bn = blockIdx.x << 7;
  const int K = 2048;

  const u16* Bp; int nb, region;
  if (bn < 2048)      { Bp = Bq; nb = bn;        region = 0; }
  else if (bn < 2560) { Bp = Bk; nb = bn - 2048; region = 1; }
  else                { Bp = Bv; nb = bn - 2560; region = 2; }

  f32x4 acc[2][4] = {};

  for (int kt = 0; kt < 32; ++kt) {
    const int k0 = kt << 6;
#pragma unroll
    for (int i = 0; i < 2; ++i) {
      const int cid = (i << 8) + tid;
      const int r = cid >> 3, c = cid & 7;
      const int cs = (c ^ (r & 7)) << 3;
      gload_lds16(A + (size_t)(bm + r) * K + k0 + cs, (char*)As + cid * 16);
    }
#pragma unroll
    for (int i = 0; i < 4; ++i) {
      const int cid = (i << 8) + tid;
      const int r = cid >> 3, c = cid & 7;
      const int cs = (c ^ (r & 7)) << 3;
      gload_lds16(Bp + (size_t)(nb + r) * K + k0 + cs, (char*)Bs + cid * 16);
    }
    __syncthreads();
    bf16x8 af[2][2], bfv[2][4];
#pragma unroll
    for (int ks = 0; ks < 2; ++ks) {
#pragma unroll
      for (int f = 0; f < 2; ++f) {
        const int ra = wr * 32 + f * 16 + lr;
        const int ca = (lq + (ks << 2)) ^ (ra & 7);
        af[ks][f] = *(const bf16x8*)&As[((ra << 3) | ca) << 3];
      }
#pragma unroll
      for (int f = 0; f < 4; ++f) {
        const int rb = wc * 64 + f * 16 + lr;
        const int cb = (lq + (ks << 2)) ^ (rb & 7);
        bfv[ks][f] = *(const bf16x8*)&Bs[((rb << 3) | cb) << 3];
      }
    }
#pragma unroll
    for (int ks = 0; ks < 2; ++ks)
#pragma unroll
      for (int mf = 0; mf < 2; ++mf)
#pragma unroll
        for (int nf = 0; nf < 4; ++nf)
          acc[mf][nf] = __builtin_amdgcn_mfma_f32_16x16x32_bf16(
              af[ks][mf], bfv[ks][nf], acc[mf][nf], 0, 0, 0);
    __syncthreads();
  }

  const int rbase = bm + wr * 32;
  const int cb64 = nb + wc * 64;
  if (region == 2) {
    const int hkv = cb64 >> 6;
#pragma unroll
    for (int mf = 0; mf < 2; ++mf) {
      const int s0 = rbase + mf * 16 + lq * 4;
#pragma unroll
      for (int nf = 0; nf < 4; ++nf) {
        const int d = (cb64 & 63) + nf * 16 + lr;
        ushort4 st;
        st.x = f2bf(acc[mf][nf][0]); st.y = f2bf(acc[mf][nf][1]);
        st.z = f2bf(acc[mf][nf][2]); st.w = f2bf(acc[mf][nf][3]);
        *(ushort4*)&Vt[(size_t)hkv * 131072 + (size_t)d * 2048 + s0] = st;
      }
    }
  } else {
    u16* outp = region ? Kb : Qb;
    const int ldo = region ? 512 : 2048;
    const float post = region ? 1.0f : 0.18033688011112042f;
#pragma unroll
    for (int mf = 0; mf < 2; ++mf)
#pragma unroll
      for (int r = 0; r < 4; ++r) {
        const int s = rbase + mf * 16 + lq * 4 + r;
        const float* cr = cosp + s * 64;
        const float* sr = sinp + s * 64;
#pragma unroll
        for (int nf = 0; nf < 2; ++nf) {
          const int d1 = nf * 16 + lr, d2 = d1 + 32;
          const float x1 = acc[mf][nf][r], x2 = acc[mf][nf + 2][r];
          const float y1 = (x1 * cr[d1] - x2 * sr[d1]) * post;
          const float y2 = (x2 * cr[d2] + x1 * sr[d2]) * post;
          outp[(size_t)s * ldo + cb64 + d1] = f2bf(y1);
          outp[(size_t)s * ldo + cb64 + d2] = f2bf(y2);
        }
      }
  }
}

// ---------------------------------------------------------------------------
// out-proj GEMM (bf16 in, f32 out), BM=64 x BN=128
// ---------------------------------------------------------------------------
__global__ __launch_bounds__(256, 4) void gemm_out(
    const u16* __restrict__ A, const u16* __restrict__ B, float* __restrict__ C,
    int M, int N, int K) {
  __shared__ u16 As[64 * 64];
  __shared__ u16 Bs[128 * 64];
  const int tid = threadIdx.x;
  const int lane = tid & 63, w = tid >> 6;
  const int wr = w >> 1, wc = w & 1;
  const int lr = lane & 15, lq = lane >> 4;
  const int bm = blockIdx.y << 6, bn = blockIdx.x << 7;

  f32x4 acc[2][4] = {};
  const int nK = K >> 6;
  for (int kt = 0; kt < nK; ++kt) {
    const int k0 = kt << 6;
#pragma unroll
    for (int i = 0; i < 2; ++i) {
      const int cid = (i << 8) + tid;
      const int r = cid >> 3, c = cid & 7;
      const int cs = (c ^ (r & 7)) << 3;
      gload_lds16(A + (size_t)(bm + r) * K + k0 + cs, (char*)As + cid * 16);
    }
#pragma unroll
    for (int i = 0; i < 4; ++i) {
      const int cid = (i << 8) + tid;
      const int r = cid >> 3, c = cid & 7;
      const int cs = (c ^ (r & 7)) << 3;
      gload_lds16(B + (size_t)(bn + r) * K + k0 + cs, (char*)Bs + cid * 16);
    }
    __syncthreads();
    bf16x8 af[2][2], bfv[2][4];
#pragma unroll
    for (int ks = 0; ks < 2; ++ks) {
#pragma unroll
      for (int f = 0; f < 2; ++f) {
        const int ra = wr * 32 + f * 16 + lr;
        const int ca = (lq + (ks << 2)) ^ (ra & 7);
        af[ks][f] = *(const bf16x8*)&As[((ra << 3) | ca) << 3];
      }
#pragma unroll
      for (int f = 0; f < 4; ++f) {
        const int rb = wc * 64 + f * 16 + lr;
        const int cb = (lq + (ks << 2)) ^ (rb & 7);
        bfv[ks][f] = *(const bf16x8*)&Bs[((rb << 3) | cb) << 3];
      }
    }
#pragma unroll
    for (int ks = 0; ks < 2; ++ks)
#pragma unroll
      for (int mf = 0; mf < 2; ++mf)
#pragma unroll
        for (int nf = 0; nf < 4; ++nf)
          acc[mf][nf] = __builtin_amdgcn_mfma_f32_16x16x32_bf16(
              af[ks][mf], bfv[ks][nf], acc[mf][nf], 0, 0, 0);
    __syncthreads();
  }
  const int rbase = bm + wr * 32;
  const int cbase = bn + wc * 64;
#pragma unroll
  for (int mf = 0; mf < 2; ++mf)
#pragma unroll
    for (int r = 0; r < 4; ++r) {
      const int s = rbase + mf * 16 + lq * 4 + r;
#pragma unroll
      for (int nf = 0; nf < 4; ++nf)
        C[(size_t)s * N + cbase + nf * 16 + lr] = acc[mf][nf][r];
    }
}

// ---------------------------------------------------------------------------
// Attention (v12 structure) as template<MODE, REPEAT> for WITHIN-PROBE
// ABLATION. MODE 0 = full (the real kernel, == v12). MODE 1 = NO-SOFTMAX:
// exp/sums/cvtpk/bpermute removed, PV consumes raw score bits (garbage
// output, timing isolates staging+MFMA+barrier floor). MODE 2 = NO-BARRIER:
// per-wave vmcnt(0) only, no s_barrier (races -> garbage; isolates the
// inter-wave convoy cost). Ablation dispatches write the same scratch
// buffers and are overwritten by the final MODE-0 dispatch, so the
// pipeline output stays correct and deterministic.
// ---------------------------------------------------------------------------
template<int MODE, int REPEAT>
__global__ __launch_bounds__(512, 4) void attn_abl(
    const u16* __restrict__ Qb, const u16* __restrict__ Kb,
    const u16* __restrict__ Vt, u16* __restrict__ P0, u16* __restrict__ P1,
    u16* __restrict__ P2, float* __restrict__ lsum) {
  __shared__ u16 Ks[2][4096];
  __shared__ u16 Vs[2][4096];
  const int hkv = blockIdx.x / 3;
  const int ck = blockIdx.x % 3;
  const int by = blockIdx.y;
  const int j = (by & 1) ? (by >> 1) : (31 - (by >> 1));
  const int tid = threadIdx.x;
  const int w = tid >> 6, lane = tid & 63;
  const int col = lane & 31, hi = lane >> 5;
  const int g = col >> 3, r = col & 7;
  const int h = hkv * 4 + g;

  const int qoff = w * 8 + r;
  const int qg = j * 64 + qoff;

  u16* Pc = (ck == 0) ? P0 : (ck == 1) ? P1 : P2;

  const u16* qp = Qb + (size_t)qg * 2048 + h * 64 + hi * 8;
  uint4 qf[4];
#pragma unroll
  for (int s = 0; s < 4; ++s) qf[s] = *(const uint4*)(qp + 16 * s);

  f32x16 o0 = {}, o1 = {};
  float l_loc = 0.f;

  auto STAGE = [&](int buf, int t) {
    const int kv0 = t << 6;
    const int rr = tid >> 3, cc = tid & 7;
    const int csw = (cc ^ (rr & 7)) << 3;
    gload_lds16(Kb + (size_t)(kv0 + rr) * 512 + hkv * 64 + csw,
                (char*)Ks + buf * 8192 + tid * 16);
    gload_lds16(Vt + (size_t)hkv * 131072 + (size_t)rr * 2048 + kv0 + csw,
                (char*)Vs + buf * 8192 + tid * 16);
  };

#pragma unroll 1
  for (int rep = 0; rep < REPEAT; ++rep) {
    if (ck <= j) {
      STAGE(0, ck);
      int i = 0;
      for (int t = ck; t <= j; t += 3, ++i) {
        const int buf = i & 1;
        if (MODE == 2) {
          asm volatile("s_waitcnt vmcnt(0)" ::: "memory");   // wave-local only
        } else {
          __syncthreads();
        }
        if (t + 3 <= j) STAGE(buf ^ 1, t + 3);
        const char* Kl = (const char*)Ks + buf * 8192;
        const char* Vl = (const char*)Vs + buf * 8192;

        f32x16 sc0 = {}, sc1 = {};
#pragma unroll
        for (int s = 0; s < 4; ++s) {
          const int c = 2 * s + hi;
          const bf16x8 k0 = *(const bf16x8*)(Kl + (((col) << 3) + (c ^ (col & 7))) * 16);
          sc0 = __builtin_amdgcn_mfma_f32_32x32x16_bf16(
              k0, __builtin_bit_cast(bf16x8, qf[s]), sc0, 0, 0, 0);
          const bf16x8 k1 = *(const bf16x8*)(Kl + (((col + 32) << 3) + (c ^ (col & 7))) * 16);
          sc1 = __builtin_amdgcn_mfma_f32_32x32x16_bf16(
              k1, __builtin_bit_cast(bf16x8, qf[s]), sc1, 0, 0, 0);
        }

        if (t == j) {
#pragma unroll
          for (int i2 = 0; i2 < 16; ++i2) {
            const int kvr = (i2 & 3) + 8 * (i2 >> 2) + 4 * hi;
            if (kvr > qoff) sc0[i2] = -1e30f;
            if (kvr + 32 > qoff) sc1[i2] = -1e30f;
          }
        }

        if (MODE == 1) {
          // NO-SOFTMAX: PV directly on raw score bits (keeps sc live, skips
          // exp/sums/pack/shfl). Output garbage; timing = structural floor.
#pragma unroll
          for (int s2 = 0; s2 < 4; ++s2) {
            uint4 pw;
            pw.x = __builtin_bit_cast(unsigned, sc0[4 * s2]);
            pw.y = __builtin_bit_cast(unsigned, sc0[4 * s2 + 1]);
            pw.z = __builtin_bit_cast(unsigned, sc1[4 * s2 + 2]);
            pw.w = __builtin_bit_cast(unsigned, sc1[4 * s2 + 3]);
            const bf16x8 pf = __builtin_bit_cast(bf16x8, pw);
            const int c = 2 * s2 + hi;
            const bf16x8 v0 = *(const bf16x8*)(Vl + (((col) << 3) + (c ^ (col & 7))) * 16);
            const bf16x8 v1 = *(const bf16x8*)(Vl + (((col + 32) << 3) + (c ^ (col & 7))) * 16);
            o0 = __builtin_amdgcn_mfma_f32_32x32x16_bf16(v0, pf, o0, 0, 0, 0);
            o1 = __builtin_amdgcn_mfma_f32_32x32x16_bf16(v1, pf, o1, 0, 0, 0);
          }
          l_loc += 1.f;
        } else {
          float p0[16], p1[16];
#pragma unroll
          for (int i2 = 0; i2 < 16; ++i2) { p0[i2] = fexp2(sc0[i2]); p1[i2] = fexp2(sc1[i2]); }

          float r0 = 0.f, r1 = 0.f, r2 = 0.f, r3 = 0.f;
#pragma unroll
          for (int i2 = 0; i2 < 4; ++i2) {
            r0 += p0[4 * i2]     + p1[4 * i2];
            r1 += p0[4 * i2 + 1] + p1[4 * i2 + 1];
            r2 += p0[4 * i2 + 2] + p1[4 * i2 + 2];
            r3 += p0[4 * i2 + 3] + p1[4 * i2 + 3];
          }
          l_loc += (r0 + r1) + (r2 + r3);

          unsigned W0a[4], W1a[4], W0b[4], W1b[4];
#pragma unroll
          for (int gg = 0; gg < 4; ++gg) {
            W0a[gg] = cvtpk(p0[4 * gg], p0[4 * gg + 1]);
            W1a[gg] = cvtpk(p0[4 * gg + 2], p0[4 * gg + 3]);
            W0b[gg] = cvtpk(p1[4 * gg], p1[4 * gg + 1]);
            W1b[gg] = cvtpk(p1[4 * gg + 2], p1[4 * gg + 3]);
          }

#pragma unroll
          for (int s2 = 0; s2 < 4; ++s2) {
            const unsigned* W0 = (s2 & 2) ? W0b : W0a;
            const unsigned* W1 = (s2 & 2) ? W1b : W1a;
            const int G = s2 & 1, ga = 2 * G, gb = 2 * G + 1;
            const unsigned sx0 = hi ? W0[ga] : W0[gb];
            const unsigned sx1 = hi ? W1[ga] : W1[gb];
            const unsigned rx0 = __shfl_xor(sx0, 32, 64);
            const unsigned rx1 = __shfl_xor(sx1, 32, 64);
            uint4 pw;
            pw.x = hi ? rx0 : W0[ga];
            pw.y = hi ? rx1 : W1[ga];
            pw.z = hi ? W0[gb] : rx0;
            pw.w = hi ? W1[gb] : rx1;
            const bf16x8 pf = __builtin_bit_cast(bf16x8, pw);
            const int c = 2 * s2 + hi;
            const bf16x8 v0 = *(const bf16x8*)(Vl + (((col) << 3) + (c ^ (col & 7))) * 16);
            const bf16x8 v1 = *(const bf16x8*)(Vl + (((col + 32) << 3) + (c ^ (col & 7))) * 16);
            o0 = __builtin_amdgcn_mfma_f32_32x32x16_bf16(v0, pf, o0, 0, 0, 0);
            o1 = __builtin_amdgcn_mfma_f32_32x32x16_bf16(v1, pf, o1, 0, 0, 0);
          }
        }
      }
    }
  }

  const float l = l_loc + __shfl_xor(l_loc, 32, 64);

  u16* op = Pc + (size_t)qg * 2048 + h * 64;
#pragma unroll
  for (int gg = 0; gg < 4; ++gg) {
    uint2 s0, s1;
    s0.x = cvtpk(o0[4 * gg], o0[4 * gg + 1]);
    s0.y = cvtpk(o0[4 * gg + 2], o0[4 * gg + 3]);
    s1.x = cvtpk(o1[4 * gg], o1[4 * gg + 1]);
    s1.y = cvtpk(o1[4 * gg + 2], o1[4 * gg + 3]);
    *(uint2*)(op + 8 * gg + 4 * hi)      = s0;
    *(uint2*)(op + 8 * gg + 4 * hi + 32) = s1;
  }
  if (hi == 0)
    lsum[(size_t)ck * 65536 + (size_t)qg * 32 + h] = l;
}

// ---------------------------------------------------------------------------
// merge 3 chunk partials in-place into P0 (absolute scale: sum/(l0+l1+l2))
// ---------------------------------------------------------------------------
__global__ __launch_bounds__(256) void attn_merge3(
    u16* __restrict__ P0, const u16* __restrict__ P1, const u16* __restrict__ P2,
    const float* __restrict__ lsum) {
  const int s = blockIdx.x;
  const int e0 = threadIdx.x * 8;
  const int h = e0 >> 6;
  const float l = lsum[(size_t)s * 32 + h] + lsum[65536 + (size_t)s * 32 + h] +
                  lsum[131072 + (size_t)s * 32 + h];
  const float inv = 1.f / l;
  uint4 a = *(const uint4*)(P0 + (size_t)s * 2048 + e0);
  uint4 b = *(const uint4*)(P1 + (size_t)s * 2048 + e0);
  uint4 d = *(const uint4*)(P2 + (size_t)s * 2048 + e0);
  const u16* pa = (const u16*)&a;
  const u16* pb = (const u16*)&b;
  const u16* pd = (const u16*)&d;
  ushort4 oA, oB;
  oA.x = f2bf((bf2f(pa[0]) + bf2f(pb[0]) + bf2f(pd[0])) * inv);
  oA.y = f2bf((bf2f(pa[1]) + bf2f(pb[1]) + bf2f(pd[1])) * inv);
  oA.z = f2bf((bf2f(pa[2]) + bf2f(pb[2]) + bf2f(pd[2])) * inv);
  oA.w = f2bf((bf2f(pa[3]) + bf2f(pb[3]) + bf2f(pd[3])) * inv);
  oB.x = f2bf((bf2f(pa[4]) + bf2f(pb[4]) + bf2f(pd[4])) * inv);
  oB.y = f2bf((bf2f(pa[5]) + bf2f(pb[5]) + bf2f(pd[5])) * inv);
  oB.z = f2bf((bf2f(pa[6]) + bf2f(pb[6]) + bf2f(pd[6])) * inv);
  oB.w = f2bf((bf2f(pa[7]) + bf2f(pb[7]) + bf2f(pd[7])) * inv);
  *(ushort4*)(P0 + (size_t)s * 2048 + e0)     = oA;
  *(ushort4*)(P0 + (size_t)s * 2048 + e0 + 4) = oB;
}

// ---------------------------------------------------------------------------
extern "C" void kernel_launch(void* const* d_in, const int* in_sizes, int n_in,
                              void* d_out, int out_size, void* d_ws, size_t ws_size,
                              hipStream_t stream) {
  const float* X    = (const float*)d_in[0];
  const float* cosp = (const float*)d_in[1];
  const float* sinp = (const float*)d_in[2];
  const float* Wq   = (const float*)d_in[3];
  const float* Wk   = (const float*)d_in[4];
  const float* Wv   = (const float*)d_in[5];
  const float* Wo   = (const float*)d_in[6];

  u16* ws  = (u16*)d_ws;
  u16* Xb  = ws;
  u16* Wqb = ws + 4194304;
  u16* Wkb = ws + 8388608;
  u16* Wvb = ws + 9437184;
  u16* Wob = ws + 10485760;
  u16* Qb  = ws + 14680064;
  u16* Kb  = ws + 18874368;
  u16* Vt  = ws + 19922944;
  u16* P2  = ws + 20971520;
  u16* P0  = Xb;
  u16* P1  = Wqb;
  float* lsum = (float*)(ws + 8388608);

  cvt_all<<<3584, 256, 0, stream>>>(X, Wq, Wk, Wv, Wo, Xb, Wqb, Wkb, Wvb, Wob);

  dim3 gqkv(24, 32), ga(24, 32), go(16, 32);
  gemm_qkv<<<gqkv, 256, 0, stream>>>(Xb, Wqb, Wkb, Wvb, Qb, Kb, Vt, cosp, sinp);

  // --- ablation dispatches (outputs overwritten by the real attn below) ---
  attn_abl<1, 3><<<ga, 512, 0, stream>>>(Qb, Kb, Vt, P0, P1, P2, lsum);  // no-softmax x3
  attn_abl<2, 3><<<ga, 512, 0, stream>>>(Qb, Kb, Vt, P0, P1, P2, lsum);  // no-barrier x3

  // --- real attention (== v12) ---
  attn_abl<0, 1><<<ga, 512, 0, stream>>>(Qb, Kb, Vt, P0, P1, P2, lsum);
  attn_merge3<<<2048, 256, 0, stream>>>(P0, P1, P2, lsum);
  gemm_out<<<go, 256, 0, stream>>>(P0, Wob, (float*)d_out, 2048, 2048, 2048);
}

// Round 16
// 121.965 us; speedup vs baseline: 2.1660x; 2.1660x over previous
//
#include <hip/hip_runtime.h>

typedef unsigned short u16;
typedef __bf16 bf16x8 __attribute__((ext_vector_type(8)));
typedef float f32x4 __attribute__((ext_vector_type(4)));
typedef float f32x16 __attribute__((ext_vector_type(16)));

static __device__ __forceinline__ u16 f2bf(float f) {
  unsigned u = __builtin_bit_cast(unsigned, f);
  u += 0x7fffu + ((u >> 16) & 1u);
  return (u16)(u >> 16);
}
static __device__ __forceinline__ float bf2f(u16 u) {
  return __builtin_bit_cast(float, (unsigned)u << 16);
}
static __device__ __forceinline__ unsigned cvtpk(float lo, float hi) {
  unsigned r;
  asm("v_cvt_pk_bf16_f32 %0, %1, %2" : "=v"(r) : "v"(lo), "v"(hi));
  return r;
}
static __device__ __forceinline__ float fexp2(float x) {
  float r;
  asm("v_exp_f32 %0, %1" : "=v"(r) : "v"(x));
  return r;
}

static __device__ __forceinline__ void gload_lds16(const void* g, void* l) {
  __builtin_amdgcn_global_load_lds((const __attribute__((address_space(1))) unsigned int*)g,
                                   (__attribute__((address_space(3))) unsigned int*)l,
                                   16, 0, 0);
}

// ---------------------------------------------------------------------------
// fp32 -> bf16 conversion for X, Wq, Wk, Wv, Wo (one launch)
// ---------------------------------------------------------------------------
__global__ __launch_bounds__(256) void cvt_all(
    const float* __restrict__ X, const float* __restrict__ Wq, const float* __restrict__ Wk,
    const float* __restrict__ Wv, const float* __restrict__ Wo,
    u16* __restrict__ oX, u16* __restrict__ oWq, u16* __restrict__ oWk,
    u16* __restrict__ oWv, u16* __restrict__ oWo) {
  const int b = blockIdx.x;
  const float* s; u16* d; int lb;
  if (b < 1024)      { s = X;  d = oX;  lb = b; }
  else if (b < 2048) { s = Wq; d = oWq; lb = b - 1024; }
  else if (b < 2304) { s = Wk; d = oWk; lb = b - 2048; }
  else if (b < 2560) { s = Wv; d = oWv; lb = b - 2304; }
  else               { s = Wo; d = oWo; lb = b - 2560; }
  const int base = lb * 4096 + threadIdx.x * 4;
#pragma unroll
  for (int j = 0; j < 4; ++j) {
    const int off = base + j * 1024;
    float4 v = *(const float4*)(s + off);
    ushort4 u;
    u.x = f2bf(v.x); u.y = f2bf(v.y); u.z = f2bf(v.z); u.w = f2bf(v.w);
    *(ushort4*)(d + off) = u;
  }
}

// ---------------------------------------------------------------------------
// Fused QKV GEMM over virtual N=3072: [Wq | Wk | Wv]. BM=64 x BN=128, BK=64.
// ---------------------------------------------------------------------------
__global__ __launch_bounds__(256, 4) void gemm_qkv(
    const u16* __restrict__ A, const u16* __restrict__ Bq, const u16* __restrict__ Bk,
    const u16* __restrict__ Bv, u16* __restrict__ Qb, u16* __restrict__ Kb,
    u16* __restrict__ Vt, const float* __restrict__ cosp, const float* __restrict__ sinp) {
  __shared__ u16 As[64 * 64];
  __shared__ u16 Bs[128 * 64];
  const int tid = threadIdx.x;
  const int lane = tid & 63, w = tid >> 6;
  const int wr = w >> 1, wc = w & 1;
  const int lr = lane & 15, lq = lane >> 4;
  const int bm = blockIdx.y << 6;
  const int bn = blockIdx.x << 7;
  const int K = 2048;

  const u16* Bp; int nb, region;
  if (bn < 2048)      { Bp = Bq; nb = bn;        region = 0; }
  else if (bn < 2560) { Bp = Bk; nb = bn - 2048; region = 1; }
  else                { Bp = Bv; nb = bn - 2560; region = 2; }

  f32x4 acc[2][4] = {};

  for (int kt = 0; kt < 32; ++kt) {
    const int k0 = kt << 6;
#pragma unroll
    for (int i = 0; i < 2; ++i) {
      const int cid = (i << 8) + tid;
      const int r = cid >> 3, c = cid & 7;
      const int cs = (c ^ (r & 7)) << 3;
      gload_lds16(A + (size_t)(bm + r) * K + k0 + cs, (char*)As + cid * 16);
    }
#pragma unroll
    for (int i = 0; i < 4; ++i) {
      const int cid = (i << 8) + tid;
      const int r = cid >> 3, c = cid & 7;
      const int cs = (c ^ (r & 7)) << 3;
      gload_lds16(Bp + (size_t)(nb + r) * K + k0 + cs, (char*)Bs + cid * 16);
    }
    __syncthreads();
    bf16x8 af[2][2], bfv[2][4];
#pragma unroll
    for (int ks = 0; ks < 2; ++ks) {
#pragma unroll
      for (int f = 0; f < 2; ++f) {
        const int ra = wr * 32 + f * 16 + lr;
        const int ca = (lq + (ks << 2)) ^ (ra & 7);
        af[ks][f] = *(const bf16x8*)&As[((ra << 3) | ca) << 3];
      }
#pragma unroll
      for (int f = 0; f < 4; ++f) {
        const int rb = wc * 64 + f * 16 + lr;
        const int cb = (lq + (ks << 2)) ^ (rb & 7);
        bfv[ks][f] = *(const bf16x8*)&Bs[((rb << 3) | cb) << 3];
      }
    }
#pragma unroll
    for (int ks = 0; ks < 2; ++ks)
#pragma unroll
      for (int mf = 0; mf < 2; ++mf)
#pragma unroll
        for (int nf = 0; nf < 4; ++nf)
          acc[mf][nf] = __builtin_amdgcn_mfma_f32_16x16x32_bf16(
              af[ks][mf], bfv[ks][nf], acc[mf][nf], 0, 0, 0);
    __syncthreads();
  }

  const int rbase = bm + wr * 32;
  const int cb64 = nb + wc * 64;
  if (region == 2) {
    const int hkv = cb64 >> 6;
#pragma unroll
    for (int mf = 0; mf < 2; ++mf) {
      const int s0 = rbase + mf * 16 + lq * 4;
#pragma unroll
      for (int nf = 0; nf < 4; ++nf) {
        const int d = (cb64 & 63) + nf * 16 + lr;
        ushort4 st;
        st.x = f2bf(acc[mf][nf][0]); st.y = f2bf(acc[mf][nf][1]);
        st.z = f2bf(acc[mf][nf][2]); st.w = f2bf(acc[mf][nf][3]);
        *(ushort4*)&Vt[(size_t)hkv * 131072 + (size_t)d * 2048 + s0] = st;
      }
    }
  } else {
    u16* outp = region ? Kb : Qb;
    const int ldo = region ? 512 : 2048;
    const float post = region ? 1.0f : 0.18033688011112042f;
#pragma unroll
    for (int mf = 0; mf < 2; ++mf)
#pragma unroll
      for (int r = 0; r < 4; ++r) {
        const int s = rbase + mf * 16 + lq * 4 + r;
        const float* cr = cosp + s * 64;
        const float* sr = sinp + s * 64;
#pragma unroll
        for (int nf = 0; nf < 2; ++nf) {
          const int d1 = nf * 16 + lr, d2 = d1 + 32;
          const float x1 = acc[mf][nf][r], x2 = acc[mf][nf + 2][r];
          const float y1 = (x1 * cr[d1] - x2 * sr[d1]) * post;
          const float y2 = (x2 * cr[d2] + x1 * sr[d2]) * post;
          outp[(size_t)s * ldo + cb64 + d1] = f2bf(y1);
          outp[(size_t)s * ldo + cb64 + d2] = f2bf(y2);
        }
      }
  }
}

// ---------------------------------------------------------------------------
// out-proj GEMM (bf16 in, f32 out), BM=64 x BN=128
// ---------------------------------------------------------------------------
__global__ __launch_bounds__(256, 4) void gemm_out(
    const u16* __restrict__ A, const u16* __restrict__ B, float* __restrict__ C,
    int M, int N, int K) {
  __shared__ u16 As[64 * 64];
  __shared__ u16 Bs[128 * 64];
  const int tid = threadIdx.x;
  const int lane = tid & 63, w = tid >> 6;
  const int wr = w >> 1, wc = w & 1;
  const int lr = lane & 15, lq = lane >> 4;
  const int bm = blockIdx.y << 6, bn = blockIdx.x << 7;

  f32x4 acc[2][4] = {};
  const int nK = K >> 6;
  for (int kt = 0; kt < nK; ++kt) {
    const int k0 = kt << 6;
#pragma unroll
    for (int i = 0; i < 2; ++i) {
      const int cid = (i << 8) + tid;
      const int r = cid >> 3, c = cid & 7;
      const int cs = (c ^ (r & 7)) << 3;
      gload_lds16(A + (size_t)(bm + r) * K + k0 + cs, (char*)As + cid * 16);
    }
#pragma unroll
    for (int i = 0; i < 4; ++i) {
      const int cid = (i << 8) + tid;
      const int r = cid >> 3, c = cid & 7;
      const int cs = (c ^ (r & 7)) << 3;
      gload_lds16(B + (size_t)(bn + r) * K + k0 + cs, (char*)Bs + cid * 16);
    }
    __syncthreads();
    bf16x8 af[2][2], bfv[2][4];
#pragma unroll
    for (int ks = 0; ks < 2; ++ks) {
#pragma unroll
      for (int f = 0; f < 2; ++f) {
        const int ra = wr * 32 + f * 16 + lr;
        const int ca = (lq + (ks << 2)) ^ (ra & 7);
        af[ks][f] = *(const bf16x8*)&As[((ra << 3) | ca) << 3];
      }
#pragma unroll
      for (int f = 0; f < 4; ++f) {
        const int rb = wc * 64 + f * 16 + lr;
        const int cb = (lq + (ks << 2)) ^ (rb & 7);
        bfv[ks][f] = *(const bf16x8*)&Bs[((rb << 3) | cb) << 3];
      }
    }
#pragma unroll
    for (int ks = 0; ks < 2; ++ks)
#pragma unroll
      for (int mf = 0; mf < 2; ++mf)
#pragma unroll
        for (int nf = 0; nf < 4; ++nf)
          acc[mf][nf] = __builtin_amdgcn_mfma_f32_16x16x32_bf16(
              af[ks][mf], bfv[ks][nf], acc[mf][nf], 0, 0, 0);
    __syncthreads();
  }
  const int rbase = bm + wr * 32;
  const int cbase = bn + wc * 64;
#pragma unroll
  for (int mf = 0; mf < 2; ++mf)
#pragma unroll
    for (int r = 0; r < 4; ++r) {
      const int s = rbase + mf * 16 + lq * 4 + r;
#pragma unroll
      for (int nf = 0; nf < 4; ++nf)
        C[(size_t)s * N + cbase + nf * 16 + lr] = acc[mf][nf][r];
    }
}

// ---------------------------------------------------------------------------
// Attention v14: v12 structure + TWO TILES PER BARRIER (ablation-driven:
// barrier convoy = ~13us, softmax serialization = ~13us). Paired buffers
// (2 pairs x 2 tiles x (K+V) = 64 KB, 2 blocks/CU), prefetch next pair under
// compute, one __syncthreads per 2 tiles. The two tiles' compute is one
// straight-line region so tile-B QK^T overlaps tile-A softmax/pack.
// No-max exp2 softmax, 3-way chunk partials, absolute-scale merge.
// ---------------------------------------------------------------------------
__global__ __launch_bounds__(512, 4) void attn_v14(
    const u16* __restrict__ Qb, const u16* __restrict__ Kb,
    const u16* __restrict__ Vt, u16* __restrict__ P0, u16* __restrict__ P1,
    u16* __restrict__ P2, float* __restrict__ lsum) {
  __shared__ u16 Ks[4][4096];   // [pair*2+slot][64 kv x 64 d] swizzled
  __shared__ u16 Vs[4][4096];   // [pair*2+slot][64 d x 64 kv] swizzled
  const int hkv = blockIdx.x / 3;
  const int ck = blockIdx.x % 3;
  const int by = blockIdx.y;
  const int j = (by & 1) ? (by >> 1) : (31 - (by >> 1));  // snake: long first
  const int tid = threadIdx.x;
  const int w = tid >> 6, lane = tid & 63;
  const int col = lane & 31, hi = lane >> 5;
  const int g = col >> 3, r = col & 7;
  const int h = hkv * 4 + g;

  const int qoff = w * 8 + r;
  const int qg = j * 64 + qoff;

  u16* Pc = (ck == 0) ? P0 : (ck == 1) ? P1 : P2;

  const u16* qp = Qb + (size_t)qg * 2048 + h * 64 + hi * 8;
  uint4 qf[4];
#pragma unroll
  for (int s = 0; s < 4; ++s) qf[s] = *(const uint4*)(qp + 16 * s);

  f32x16 o0 = {}, o1 = {};
  float l_loc = 0.f;

  // stage one 64-kv tile into slot: 512 thr -> 1 K chunk + 1 V chunk each
  auto STAGE1 = [&](int slot, int t) {
    const int kv0 = t << 6;
    const int rr = tid >> 3, cc = tid & 7;
    const int csw = (cc ^ (rr & 7)) << 3;
    gload_lds16(Kb + (size_t)(kv0 + rr) * 512 + hkv * 64 + csw,
                (char*)Ks + slot * 8192 + tid * 16);
    gload_lds16(Vt + (size_t)hkv * 131072 + (size_t)rr * 2048 + kv0 + csw,
                (char*)Vs + slot * 8192 + tid * 16);
  };
  // stage a pair (t, t+3) into pair-buffer pb
  auto STAGE2 = [&](int pb, int t) {
    STAGE1(pb * 2, t);
    if (t + 3 <= j) STAGE1(pb * 2 + 1, t + 3);
  };

  // full per-tile compute (QK^T -> exp2 -> pack -> PV); diag is uniform
  auto TILE = [&](const char* Kl, const char* Vl, bool diag) {
    f32x16 sc0 = {}, sc1 = {};
#pragma unroll
    for (int s = 0; s < 4; ++s) {
      const int c = 2 * s + hi;
      const bf16x8 k0 = *(const bf16x8*)(Kl + (((col) << 3) + (c ^ (col & 7))) * 16);
      sc0 = __builtin_amdgcn_mfma_f32_32x32x16_bf16(
          k0, __builtin_bit_cast(bf16x8, qf[s]), sc0, 0, 0, 0);
      const bf16x8 k1 = *(const bf16x8*)(Kl + (((col + 32) << 3) + (c ^ (col & 7))) * 16);
      sc1 = __builtin_amdgcn_mfma_f32_32x32x16_bf16(
          k1, __builtin_bit_cast(bf16x8, qf[s]), sc1, 0, 0, 0);
    }
    if (diag) {
#pragma unroll
      for (int i2 = 0; i2 < 16; ++i2) {
        const int kvr = (i2 & 3) + 8 * (i2 >> 2) + 4 * hi;
        if (kvr > qoff) sc0[i2] = -1e30f;
        if (kvr + 32 > qoff) sc1[i2] = -1e30f;
      }
    }
    float p0[16], p1[16];
#pragma unroll
    for (int i2 = 0; i2 < 16; ++i2) { p0[i2] = fexp2(sc0[i2]); p1[i2] = fexp2(sc1[i2]); }
    float r0 = 0.f, r1 = 0.f, r2 = 0.f, r3 = 0.f;
#pragma unroll
    for (int i2 = 0; i2 < 4; ++i2) {
      r0 += p0[4 * i2]     + p1[4 * i2];
      r1 += p0[4 * i2 + 1] + p1[4 * i2 + 1];
      r2 += p0[4 * i2 + 2] + p1[4 * i2 + 2];
      r3 += p0[4 * i2 + 3] + p1[4 * i2 + 3];
    }
    l_loc += (r0 + r1) + (r2 + r3);
    unsigned W0a[4], W1a[4], W0b[4], W1b[4];
#pragma unroll
    for (int gg = 0; gg < 4; ++gg) {
      W0a[gg] = cvtpk(p0[4 * gg], p0[4 * gg + 1]);
      W1a[gg] = cvtpk(p0[4 * gg + 2], p0[4 * gg + 3]);
      W0b[gg] = cvtpk(p1[4 * gg], p1[4 * gg + 1]);
      W1b[gg] = cvtpk(p1[4 * gg + 2], p1[4 * gg + 3]);
    }
#pragma unroll
    for (int s2 = 0; s2 < 4; ++s2) {
      const unsigned* W0 = (s2 & 2) ? W0b : W0a;
      const unsigned* W1 = (s2 & 2) ? W1b : W1a;
      const int G = s2 & 1, ga = 2 * G, gb = 2 * G + 1;
      const unsigned sx0 = hi ? W0[ga] : W0[gb];
      const unsigned sx1 = hi ? W1[ga] : W1[gb];
      const unsigned rx0 = __shfl_xor(sx0, 32, 64);
      const unsigned rx1 = __shfl_xor(sx1, 32, 64);
      uint4 pw;
      pw.x = hi ? rx0 : W0[ga];
      pw.y = hi ? rx1 : W1[ga];
      pw.z = hi ? W0[gb] : rx0;
      pw.w = hi ? W1[gb] : rx1;
      const bf16x8 pf = __builtin_bit_cast(bf16x8, pw);
      const int c = 2 * s2 + hi;
      const bf16x8 v0 = *(const bf16x8*)(Vl + (((col) << 3) + (c ^ (col & 7))) * 16);
      const bf16x8 v1 = *(const bf16x8*)(Vl + (((col + 32) << 3) + (c ^ (col & 7))) * 16);
      o0 = __builtin_amdgcn_mfma_f32_32x32x16_bf16(v0, pf, o0, 0, 0, 0);
      o1 = __builtin_amdgcn_mfma_f32_32x32x16_bf16(v1, pf, o1, 0, 0, 0);
    }
  };

  if (ck <= j) {
    STAGE2(0, ck);
    int ipair = 0;
    for (int t = ck; t <= j; t += 6, ++ipair) {
      const int pb = ipair & 1;
      __syncthreads();                           // pair staged; others done
      if (t + 6 <= j) STAGE2(pb ^ 1, t + 6);     // prefetch next pair
      // tile A (t)
      TILE((const char*)Ks + (pb * 2) * 8192,
           (const char*)Vs + (pb * 2) * 8192, t == j);
      // tile B (t+3), same barrier window
      if (t + 3 <= j)
        TILE((const char*)Ks + (pb * 2 + 1) * 8192,
             (const char*)Vs + (pb * 2 + 1) * 8192, t + 3 == j);
    }
  }

  const float l = l_loc + __shfl_xor(l_loc, 32, 64);

  u16* op = Pc + (size_t)qg * 2048 + h * 64;
#pragma unroll
  for (int gg = 0; gg < 4; ++gg) {
    uint2 s0, s1;
    s0.x = cvtpk(o0[4 * gg], o0[4 * gg + 1]);
    s0.y = cvtpk(o0[4 * gg + 2], o0[4 * gg + 3]);
    s1.x = cvtpk(o1[4 * gg], o1[4 * gg + 1]);
    s1.y = cvtpk(o1[4 * gg + 2], o1[4 * gg + 3]);
    *(uint2*)(op + 8 * gg + 4 * hi)      = s0;
    *(uint2*)(op + 8 * gg + 4 * hi + 32) = s1;
  }
  if (hi == 0)
    lsum[(size_t)ck * 65536 + (size_t)qg * 32 + h] = l;
}

// ---------------------------------------------------------------------------
// merge 3 chunk partials in-place into P0 (absolute scale: sum/(l0+l1+l2))
// ---------------------------------------------------------------------------
__global__ __launch_bounds__(256) void attn_merge3(
    u16* __restrict__ P0, const u16* __restrict__ P1, const u16* __restrict__ P2,
    const float* __restrict__ lsum) {
  const int s = blockIdx.x;
  const int e0 = threadIdx.x * 8;
  const int h = e0 >> 6;
  const float l = lsum[(size_t)s * 32 + h] + lsum[65536 + (size_t)s * 32 + h] +
                  lsum[131072 + (size_t)s * 32 + h];
  const float inv = 1.f / l;
  uint4 a = *(const uint4*)(P0 + (size_t)s * 2048 + e0);
  uint4 b = *(const uint4*)(P1 + (size_t)s * 2048 + e0);
  uint4 d = *(const uint4*)(P2 + (size_t)s * 2048 + e0);
  const u16* pa = (const u16*)&a;
  const u16* pb = (const u16*)&b;
  const u16* pd = (const u16*)&d;
  ushort4 oA, oB;
  oA.x = f2bf((bf2f(pa[0]) + bf2f(pb[0]) + bf2f(pd[0])) * inv);
  oA.y = f2bf((bf2f(pa[1]) + bf2f(pb[1]) + bf2f(pd[1])) * inv);
  oA.z = f2bf((bf2f(pa[2]) + bf2f(pb[2]) + bf2f(pd[2])) * inv);
  oA.w = f2bf((bf2f(pa[3]) + bf2f(pb[3]) + bf2f(pd[3])) * inv);
  oB.x = f2bf((bf2f(pa[4]) + bf2f(pb[4]) + bf2f(pd[4])) * inv);
  oB.y = f2bf((bf2f(pa[5]) + bf2f(pb[5]) + bf2f(pd[5])) * inv);
  oB.z = f2bf((bf2f(pa[6]) + bf2f(pb[6]) + bf2f(pd[6])) * inv);
  oB.w = f2bf((bf2f(pa[7]) + bf2f(pb[7]) + bf2f(pd[7])) * inv);
  *(ushort4*)(P0 + (size_t)s * 2048 + e0)     = oA;
  *(ushort4*)(P0 + (size_t)s * 2048 + e0 + 4) = oB;
}

// ---------------------------------------------------------------------------
extern "C" void kernel_launch(void* const* d_in, const int* in_sizes, int n_in,
                              void* d_out, int out_size, void* d_ws, size_t ws_size,
                              hipStream_t stream) {
  const float* X    = (const float*)d_in[0];
  const float* cosp = (const float*)d_in[1];
  const float* sinp = (const float*)d_in[2];
  const float* Wq   = (const float*)d_in[3];
  const float* Wk   = (const float*)d_in[4];
  const float* Wv   = (const float*)d_in[5];
  const float* Wo   = (const float*)d_in[6];

  u16* ws  = (u16*)d_ws;
  u16* Xb  = ws;
  u16* Wqb = ws + 4194304;
  u16* Wkb = ws + 8388608;
  u16* Wvb = ws + 9437184;
  u16* Wob = ws + 10485760;
  u16* Qb  = ws + 14680064;
  u16* Kb  = ws + 18874368;
  u16* Vt  = ws + 19922944;
  u16* P2  = ws + 20971520;
  u16* P0  = Xb;
  u16* P1  = Wqb;
  float* lsum = (float*)(ws + 8388608);

  cvt_all<<<3584, 256, 0, stream>>>(X, Wq, Wk, Wv, Wo, Xb, Wqb, Wkb, Wvb, Wob);

  dim3 gqkv(24, 32), ga(24, 32), go(16, 32);
  gemm_qkv<<<gqkv, 256, 0, stream>>>(Xb, Wqb, Wkb, Wvb, Qb, Kb, Vt, cosp, sinp);
  attn_v14<<<ga, 512, 0, stream>>>(Qb, Kb, Vt, P0, P1, P2, lsum);
  attn_merge3<<<2048, 256, 0, stream>>>(P0, P1, P2, lsum);
  gemm_out<<<go, 256, 0, stream>>>(P0, Wob, (float*)d_out, 2048, 2048, 2048);
}